// Round 20
// baseline (373.937 us; speedup 1.0000x reference)
//
#include <hip/hip_runtime.h>
#include <math.h>

constexpr int NA   = 16000;
constexpr int NE   = 256000;
constexpr int F    = 128;
constexpr int NF   = 32;
constexpr int NRBF = 20;
constexpr float CUTOFF       = 5.0f;
constexpr float INV_SQRT_F   = 0.0883883476483184f;  // 1/sqrt(128)
constexpr float INV_SQRT_2NF = 0.125f;               // 1/sqrt(64)
constexpr float INV_SQ3      = 0.5773502691896258f;
constexpr float SQ3          = 1.7320508075688772f;
constexpr float LOG2_        = 0.6931471805599453f;
constexpr float PI_          = 3.14159265358979323f;

typedef _Float16 h2 __attribute__((ext_vector_type(2)));

__device__ __forceinline__ float ssp(float x) {
    return fmaxf(x, 0.0f) + __logf(1.0f + __expf(-fabsf(x))) - LOG2_;
}
__device__ __forceinline__ float fdot2(h2 a, h2 b, float c) {
#if __has_builtin(__builtin_amdgcn_fdot2)
    return __builtin_amdgcn_fdot2(a, b, c, false);
#else
    return c + (float)a[0]*(float)b[0] + (float)a[1]*(float)b[1];
#endif
}

// ---------------------------------------------------------------- K0: per-edge geometry
__global__ void geom_kernel(const float* __restrict__ r_ij,
                            h2* __restrict__ fijH,
                            float* __restrict__ yvrT) {
    int e = blockIdx.x * blockDim.x + threadIdx.x;
    if (e >= NE) return;
    float x = r_ij[3*e+0], y = r_ij[3*e+1], z = r_ij[3*e+2];
    float d = sqrtf(x*x + y*y + z*z);
    const float delta = CUTOFF / (NRBF - 1);
    const float coeff = -0.5f / (delta * delta);
    float f[NRBF];
    #pragma unroll
    for (int k = 0; k < NRBF; k++) {
        float t = d - delta * (float)k;
        f[k] = __expf(coeff * t * t);
    }
    #pragma unroll
    for (int k2 = 0; k2 < 10; k2++)
        fijH[(size_t)k2*NE + e] = h2{(_Float16)f[2*k2], (_Float16)f[2*k2+1]};
    float rc = 0.5f * (__cosf(PI_ * d / CUTOFF) + 1.0f);
    rc = (d < CUTOFF) ? rc : 0.0f;
    float inv = SQ3 / fmaxf(d, 1e-9f);
    yvrT[0*(size_t)NE + e] = x * inv;
    yvrT[1*(size_t)NE + e] = y * inv;
    yvrT[2*(size_t)NE + e] = z * inv;
    yvrT[3*(size_t)NE + e] = rc;
}

// ---------------------------------------------------------------- preph: f16 filter weights
__global__ void preph_kernel(const float* __restrict__ Wf2, const float* __restrict__ Wf1,
                             h2* __restrict__ Wf2H, h2* __restrict__ Wf1H) {
    int u = blockIdx.x * 256 + threadIdx.x;
    if (u < 3*128*16) {
        int l = u / (128*16), rem = u % (128*16), c = rem >> 4, k2 = rem & 15;
        const float* W = Wf2 + (size_t)l*NF*192;
        Wf2H[u] = h2{(_Float16)W[(2*k2)*192 + c], (_Float16)W[(2*k2+1)*192 + c]};
    }
    if (u < 3*320) {
        int l = u / 320, rem = u % 320, k2 = rem >> 5, g = rem & 31;
        const float* W = Wf1 + (size_t)l*NRBF*NF;
        Wf1H[u] = h2{(_Float16)W[(2*k2)*32 + g], (_Float16)W[(2*k2+1)*32 + g]};
    }
}

// ---------------------------------------------------------------- prep2: AvBv[l][f][c] = (Av[l]@Bv[l]) * scale
__global__ void prep2_kernel(const float* __restrict__ Av, const float* __restrict__ Bv,
                             float* __restrict__ AvBv) {
    int u = blockIdx.x * 256 + threadIdx.x;
    if (u >= 3*64*128) return;
    int l = u >> 13, rem = u & 8191, f = rem >> 7, c = rem & 127;
    const float* av = Av + (size_t)l*64*128 + f*128;
    const float* bv = Bv + (size_t)l*128*128 + c;
    float acc = 0.f;
    #pragma unroll 8
    for (int g = 0; g < 128; g++) acc += av[g] * bv[(size_t)g*128];
    AvBv[u] = acc * (INV_SQRT_2NF * INV_SQRT_F);
}

// ---------------------------------------------------------------- K2: xs = emb[Z] @ W_pe (32 atoms/block) + fused hsv(l=0) (f16)
__global__ __launch_bounds__(256, 4)
void embed_kernel(const int* __restrict__ Z,
                  const float* __restrict__ emb,
                  const float* __restrict__ Wpe,
                  const float* __restrict__ W0s,
                  float* __restrict__ xs,
                  _Float16* __restrict__ hsv) {
    __shared__ float ER[32][128];
    __shared__ int   Zs[32];
    int t = threadIdx.x;
    int a0 = blockIdx.x * 32;
    if (t < 32) Zs[t] = Z[a0 + t];
    __syncthreads();
    {
        const float4* emb4 = (const float4*)emb;
        float4* ER4 = (float4*)&ER[0][0];
        #pragma unroll
        for (int it = 0; it < 4; it++) {
            int u4 = it*256 + t;
            int a = u4 >> 5, k4 = u4 & 31;
            ER4[u4] = emb4[(size_t)Zs[a]*32 + k4];
        }
    }
    __syncthreads();
    int c = t & 127, half = t >> 7;
    float acc[16];
    #pragma unroll
    for (int a = 0; a < 16; a++) acc[a] = 0.f;
    for (int k = 0; k < 128; k++) {
        float w = Wpe[k*128 + c];
        #pragma unroll
        for (int a = 0; a < 16; a++) acc[a] += ER[half*16 + a][k] * w;
    }
    __syncthreads();
    #pragma unroll
    for (int a = 0; a < 16; a++) {
        float v = acc[a] * INV_SQRT_F;
        xs[(size_t)(a0 + half*16 + a)*128 + c] = v;
        ER[half*16 + a][c] = v;
    }
    __syncthreads();
    {
        int g = t & 31, rr = t >> 5;
        float a2[4] = {0.f, 0.f, 0.f, 0.f};
        for (int k = 0; k < 128; k++) {
            float w = W0s[k*32 + g];
            #pragma unroll
            for (int a = 0; a < 4; a++) a2[a] += ER[rr*4 + a][k] * w;
        }
        #pragma unroll
        for (int a = 0; a < 4; a++)
            hsv[(size_t)(a0 + rr*4 + a)*128 + g] = (_Float16)(a2[a] * INV_SQRT_F);
        for (int u = t; u < 32*96; u += 256) {
            int a = u / 96, rem = u - a*96;
            hsv[(size_t)(a0 + a)*128 + 32 + rem] = (_Float16)0.f;
        }
    }
}

// ---------------------------------------------------------------- K3: hsv projection (16 atoms/block), l=1,2 (f16 out)
__global__ __launch_bounds__(256, 4)
void h_kernel(const float* __restrict__ xs,
              const float* __restrict__ xv,
              const float* __restrict__ W0s,
              const float* __restrict__ W0v,
              _Float16* __restrict__ hsv) {
    __shared__ float X[16][512];
    int t = threadIdx.x;
    int a0 = blockIdx.x * 16;
    {
        float* Xf = &X[0][0];
        const float4* xs4 = (const float4*)xs;
        const float4* xv4 = (const float4*)xv;
        #pragma unroll
        for (int it = 0; it < 2; it++) {
            int u4 = it*256 + t;
            int a = u4 >> 5, k4 = u4 & 31;
            *(float4*)&Xf[a*512 + k4*4] = xs4[(size_t)a0*32 + u4];
        }
        #pragma unroll
        for (int it = 0; it < 6; it++) {
            int u4 = it*256 + t;
            int a = u4 / 96, rem = u4 - a*96;
            *(float4*)&Xf[a*512 + 128 + rem*4] = xv4[(size_t)a0*96 + u4];
        }
    }
    __syncthreads();
    int g = t & 31, r = t >> 5;
    int sel = r & 3, half = r >> 2;
    const float* W = (sel == 0) ? W0s : W0v;
    int xoff = (sel == 0) ? 0 : (128 + (sel-1)*128);
    float acc[8];
    #pragma unroll
    for (int a = 0; a < 8; a++) acc[a] = 0.f;
    for (int k = 0; k < 128; k++) {
        float w = W[k*32 + g];
        #pragma unroll
        for (int a = 0; a < 8; a++) acc[a] += X[half*8 + a][xoff + k] * w;
    }
    #pragma unroll
    for (int a = 0; a < 8; a++) {
        int n = a0 + half*8 + a;
        if (sel == 0) hsv[(size_t)n*128 + g] = (_Float16)(acc[a] * INV_SQRT_F);
        else          hsv[(size_t)n*128 + 32 + g*3 + (sel-1)] = (_Float16)(acc[a] * INV_SQRT_F);
    }
}

// ---------------------------------------------------------------- K4: edge aggregation, 64 edges/wave, depth-2 pipeline
struct alignas(16) HRow { h2 v[20]; };      // padded to 80B rows

template <bool DO_V>
__global__ __launch_bounds__(256, 4)
void agg_kernel(const int* __restrict__ idx_i,
                const int* __restrict__ idx_j,
                const h2* __restrict__ fijH,
                const float* __restrict__ yvrT,
                const _Float16* __restrict__ hsv,
                const h2* __restrict__ Wf1H,
                const float* __restrict__ bf1,
                const h2* __restrict__ Wf2H,
                const float* __restrict__ bf2,
                float* __restrict__ aggG) {
    __shared__ h2 LW1[320];          // 1280 B
    __shared__ HRow HB[4][64];       // 20480 B
    int t = threadIdx.x;
    for (int u = t; u < 320; u += 256) LW1[u] = Wf1H[u];
    __syncthreads();

    int wid = t >> 6, lane = t & 63;
    int base = (blockIdx.x*4 + wid) * 64;

    int   il = idx_i[base + lane];
    int   jl = idx_j[base + lane];
    float y0l = yvrT[0*(size_t)NE + base + lane];
    float y1l = yvrT[1*(size_t)NE + base + lane];
    float y2l = yvrT[2*(size_t)NE + base + lane];
    float y3l = yvrT[3*(size_t)NE + base + lane];

    int ilp = __shfl_up(il, 1);
    unsigned long long bmask = __ballot(lane > 0 && il != ilp);

    // ---- MLP1, lane-per-edge, fdot2 ----
    h2 fp[10];
    #pragma unroll
    for (int k2 = 0; k2 < 10; k2++)
        fp[k2] = fijH[(size_t)k2*NE + base + lane];
    float h[32];
    #pragma unroll
    for (int g = 0; g < 32; g++) h[g] = bf1[g];
    #pragma unroll
    for (int k2 = 0; k2 < 10; k2++) {
        #pragma unroll
        for (int g = 0; g < 32; g++)
            h[g] = fdot2(fp[k2], LW1[k2*32 + g], h[g]);
    }
    #pragma unroll
    for (int g = 0; g < 32; g++) h[g] = ssp(h[g]);
    {
        h2 hp[16];
        #pragma unroll
        for (int i = 0; i < 16; i++) hp[i] = h2{(_Float16)h[2*i], (_Float16)h[2*i+1]};
        float4* dst = (float4*)HB[wid][lane].v;
        const float4* srcp = (const float4*)hp;
        #pragma unroll
        for (int w = 0; w < 4; w++) dst[w] = srcp[w];
    }

    // ---- per-lane f16 weight columns; asm barrier blocks rematerialization ----
    h2 w2a[16], w2b[16];
    #pragma unroll
    for (int k2 = 0; k2 < 16; k2++) {
        w2a[k2] = Wf2H[lane*16 + k2];
        asm volatile("" : "+v"(w2a[k2]));
    }
    if (DO_V) {
        #pragma unroll
        for (int k2 = 0; k2 < 16; k2++) {
            w2b[k2] = Wf2H[(64+lane)*16 + k2];
            asm volatile("" : "+v"(w2b[k2]));
        }
    }
    float bf2a = bf2[lane];
    float bf2b = DO_V ? bf2[64 + lane] : 0.f;

    int idxQ = 32 + 3*(lane - 32);
    int off0 = (lane < 32) ? lane : idxQ;
    int off1 = (lane < 32) ? lane : (idxQ + 1);
    int off2 = (lane < 32) ? lane : (idxQ + 2);

    float a0 = 0.f, a1 = 0.f, a2 = 0.f, a3 = 0.f;
    int prev = __builtin_amdgcn_readlane(il, 0);

    auto body = [&](int gi, float q0, float q1, float q2, const float4* hbc) {
        if ((bmask >> gi) & 1ull) {
            unsafeAtomicAdd(&aggG[(size_t)prev*256 + lane], a0);
            a0 = 0.f;
            if (DO_V) {
                unsafeAtomicAdd(&aggG[(size_t)prev*256 + 64 + lane],  a1);
                unsafeAtomicAdd(&aggG[(size_t)prev*256 + 128 + lane], a2);
                unsafeAtomicAdd(&aggG[(size_t)prev*256 + 192 + lane], a3);
                a1 = a2 = a3 = 0.f;
            }
            prev = __builtin_amdgcn_readlane(il, gi);
        }
        float s0 = bf2a, s1 = bf2b;
        const h2* hh = (const h2*)hbc;
        #pragma unroll
        for (int k2 = 0; k2 < 16; k2++) {
            s0 = fdot2(hh[k2], w2a[k2], s0);
            if (DO_V) s1 = fdot2(hh[k2], w2b[k2], s1);
        }
        float y3s = __int_as_float(__builtin_amdgcn_readlane(__float_as_int(y3l), gi));
        float y0s = __int_as_float(__builtin_amdgcn_readlane(__float_as_int(y0l), gi));
        float y1s = __int_as_float(__builtin_amdgcn_readlane(__float_as_int(y1l), gi));
        float y2s = __int_as_float(__builtin_amdgcn_readlane(__float_as_int(y2l), gi));
        float w0 = s0 * y3s;
        float dot = (q0*y0s + q1*y1s + q2*y2s) * INV_SQ3;
        float v0 = (lane < 32) ? q0 : dot;
        a0 += v0 * w0;
        if (DO_V) {
            float w1 = s1 * y3s;
            float m1 = (lane < 32) ? y0s : 1.0f;
            float m2 = (lane < 32) ? y1s : 1.0f;
            float m3 = (lane < 32) ? y2s : 1.0f;
            a1 += q0 * m1 * w1;
            a2 += q1 * m2 * w1;
            a3 += q2 * m3 * w1;
        }
    };

    // ---- depth-2 pipelined loop (A/B q sets, per-iter HB prefetch) ----
    float qA0, qA1, qA2, qB0, qB1, qB2;
    {
        int j0 = __builtin_amdgcn_readlane(jl, 0);
        const _Float16* r0 = hsv + (size_t)j0*128;
        qA0 = (float)r0[off0]; qA1 = (float)r0[off1]; qA2 = (float)r0[off2];
        int j1 = __builtin_amdgcn_readlane(jl, 1);
        const _Float16* r1 = hsv + (size_t)j1*128;
        qB0 = (float)r1[off0]; qB1 = (float)r1[off1]; qB2 = (float)r1[off2];
    }
    float4 hbA[4];
    {
        const float4* p = (const float4*)HB[wid][0].v;
        hbA[0] = p[0]; hbA[1] = p[1]; hbA[2] = p[2]; hbA[3] = p[3];
    }
    for (int ii = 0; ii < 64; ii += 2) {
        float4 hbB[4];
        {
            const float4* p = (const float4*)HB[wid][ii+1].v;
            hbB[0] = p[0]; hbB[1] = p[1]; hbB[2] = p[2]; hbB[3] = p[3];
        }
        float cq0 = qA0, cq1 = qA1, cq2 = qA2;
        if (ii + 2 < 64) {
            int j = __builtin_amdgcn_readlane(jl, ii + 2);
            const _Float16* row = hsv + (size_t)j*128;
            qA0 = (float)row[off0]; qA1 = (float)row[off1]; qA2 = (float)row[off2];
        }
        body(ii, cq0, cq1, cq2, hbA);
        if (ii + 2 < 64) {
            const float4* p = (const float4*)HB[wid][ii+2].v;
            hbA[0] = p[0]; hbA[1] = p[1]; hbA[2] = p[2]; hbA[3] = p[3];
        }
        float dq0 = qB0, dq1 = qB1, dq2 = qB2;
        if (ii + 3 < 64) {
            int j = __builtin_amdgcn_readlane(jl, ii + 3);
            const _Float16* row = hsv + (size_t)j*128;
            qB0 = (float)row[off0]; qB1 = (float)row[off1]; qB2 = (float)row[off2];
        }
        body(ii + 1, dq0, dq1, dq2, hbB);
    }
    unsafeAtomicAdd(&aggG[(size_t)prev*256 + lane], a0);
    if (DO_V) {
        unsafeAtomicAdd(&aggG[(size_t)prev*256 + 64 + lane],  a1);
        unsafeAtomicAdd(&aggG[(size_t)prev*256 + 128 + lane], a2);
        unsafeAtomicAdd(&aggG[(size_t)prev*256 + 192 + lane], a3);
    }
}

// ---------------------------------------------------------------- K5: batched atom-side MLP (re-zeros aggG for next layer)
template <bool DO_V, bool XV_WRITE, bool ZERO_AGG>
__global__ __launch_bounds__(256, 4)
void mlp_kernel(const float* __restrict__ aggG,
                const float* __restrict__ As,
                const float* __restrict__ Bs,
                const float* __restrict__ AvBv,
                float* __restrict__ xs,
                float* __restrict__ xv,
                float* __restrict__ aggW) {
    constexpr int AC = DO_V ? 256 : 64;
    __shared__ float aggL[16][AC];
    __shared__ float outL[16][128];
    int t = threadIdx.x;
    int a0 = blockIdx.x * 16;
    {
        const float4* g4 = (const float4*)(aggG + (size_t)a0*256);
        if (DO_V) {
            float4* l4 = (float4*)&aggL[0][0];
            #pragma unroll
            for (int it = 0; it < 4; it++) l4[it*256 + t] = g4[it*256 + t];
        } else {
            int row = t >> 4, c4 = t & 15;
            *(float4*)&aggL[row][c4*4] = g4[row*64 + c4];
        }
    }
    __syncthreads();
    if (ZERO_AGG) {
        float4 z = make_float4(0.f, 0.f, 0.f, 0.f);
        float4* g4w = (float4*)(aggW + (size_t)a0*256);
        #pragma unroll
        for (int it = 0; it < 4; it++) g4w[it*256 + t] = z;
    }

    int q  = t & 31;
    int rp = t >> 5;
    const float4* As4 = (const float4*)As;
    const float4* Bs4 = (const float4*)Bs;

    {
        float ox0=0,oy0=0,oz0=0,ow0=0, ox1=0,oy1=0,oz1=0,ow1=0;
        const float4* x0p = (const float4*)&aggL[rp][0];
        const float4* x1p = (const float4*)&aggL[rp+8][0];
        #pragma unroll 4
        for (int kq = 0; kq < 16; kq++) {
            float4 x0 = x0p[kq], x1 = x1p[kq];
            float4 wa = As4[(4*kq+0)*32 + q];
            float4 wb = As4[(4*kq+1)*32 + q];
            float4 wc = As4[(4*kq+2)*32 + q];
            float4 wd = As4[(4*kq+3)*32 + q];
            ox0 += x0.x*wa.x + x0.y*wb.x + x0.z*wc.x + x0.w*wd.x;
            oy0 += x0.x*wa.y + x0.y*wb.y + x0.z*wc.y + x0.w*wd.y;
            oz0 += x0.x*wa.z + x0.y*wb.z + x0.z*wc.z + x0.w*wd.z;
            ow0 += x0.x*wa.w + x0.y*wb.w + x0.z*wc.w + x0.w*wd.w;
            ox1 += x1.x*wa.x + x1.y*wb.x + x1.z*wc.x + x1.w*wd.x;
            oy1 += x1.x*wa.y + x1.y*wb.y + x1.z*wc.y + x1.w*wd.y;
            oz1 += x1.x*wa.z + x1.y*wb.z + x1.z*wc.z + x1.w*wd.z;
            ow1 += x1.x*wa.w + x1.y*wb.w + x1.z*wc.w + x1.w*wd.w;
        }
        float4 r0 = { ssp(ox0*INV_SQRT_2NF), ssp(oy0*INV_SQRT_2NF), ssp(oz0*INV_SQRT_2NF), ssp(ow0*INV_SQRT_2NF) };
        float4 r1 = { ssp(ox1*INV_SQRT_2NF), ssp(oy1*INV_SQRT_2NF), ssp(oz1*INV_SQRT_2NF), ssp(ow1*INV_SQRT_2NF) };
        *(float4*)&outL[rp][4*q]   = r0;
        *(float4*)&outL[rp+8][4*q] = r1;
    }
    if (DO_V) {
        const float4* AB4 = (const float4*)AvBv;
        int ra[6], rc[6];
        #pragma unroll
        for (int i = 0; i < 6; i++) {
            int rv = rp + 8*i;
            ra[i] = rv/3; rc[i] = rv - 3*(rv/3);
        }
        float o[6][4];
        #pragma unroll
        for (int i = 0; i < 6; i++) { o[i][0]=0; o[i][1]=0; o[i][2]=0; o[i][3]=0; }
        const float4* vp[6];
        #pragma unroll
        for (int i = 0; i < 6; i++)
            vp[i] = (const float4*)&aggL[ra[i]][64 + rc[i]*64];
        #pragma unroll 2
        for (int kq = 0; kq < 16; kq++) {
            float4 wa = AB4[(4*kq+0)*32 + q];
            float4 wb = AB4[(4*kq+1)*32 + q];
            float4 wc = AB4[(4*kq+2)*32 + q];
            float4 wd = AB4[(4*kq+3)*32 + q];
            #pragma unroll
            for (int i = 0; i < 6; i++) {
                float4 x = vp[i][kq];
                o[i][0] += x.x*wa.x + x.y*wb.x + x.z*wc.x + x.w*wd.x;
                o[i][1] += x.x*wa.y + x.y*wb.y + x.z*wc.y + x.w*wd.y;
                o[i][2] += x.x*wa.z + x.y*wb.z + x.z*wc.z + x.w*wd.z;
                o[i][3] += x.x*wa.w + x.y*wb.w + x.z*wc.w + x.w*wd.w;
            }
        }
        #pragma unroll
        for (int i = 0; i < 6; i++) {
            float4* p = (float4*)&xv[(size_t)(a0+ra[i])*384 + rc[i]*128 + 4*q];
            if (XV_WRITE) {
                float4 c = make_float4(o[i][0], o[i][1], o[i][2], o[i][3]);
                *p = c;
            } else {
                float4 c = *p;
                c.x += o[i][0]; c.y += o[i][1]; c.z += o[i][2]; c.w += o[i][3];
                *p = c;
            }
        }
    }
    __syncthreads();
    {
        float ox0=0,oy0=0,oz0=0,ow0=0, ox1=0,oy1=0,oz1=0,ow1=0;
        const float4* x0p = (const float4*)&outL[rp][0];
        const float4* x1p = (const float4*)&outL[rp+8][0];
        #pragma unroll 4
        for (int kq = 0; kq < 32; kq++) {
            float4 x0 = x0p[kq], x1 = x1p[kq];
            float4 wa = Bs4[(4*kq+0)*32 + q];
            float4 wb = Bs4[(4*kq+1)*32 + q];
            float4 wc = Bs4[(4*kq+2)*32 + q];
            float4 wd = Bs4[(4*kq+3)*32 + q];
            ox0 += x0.x*wa.x + x0.y*wb.x + x0.z*wc.x + x0.w*wd.x;
            oy0 += x0.x*wa.y + x0.y*wb.y + x0.z*wc.y + x0.w*wd.y;
            oz0 += x0.x*wa.z + x0.y*wb.z + x0.z*wc.z + x0.w*wd.z;
            ow0 += x0.x*wa.w + x0.y*wb.w + x0.z*wc.w + x0.w*wd.w;
            ox1 += x1.x*wa.x + x1.y*wb.x + x1.z*wc.x + x1.w*wd.x;
            oy1 += x1.x*wa.y + x1.y*wb.y + x1.z*wc.y + x1.w*wd.y;
            oz1 += x1.x*wa.z + x1.y*wb.z + x1.z*wc.z + x1.w*wd.z;
            ow1 += x1.x*wa.w + x1.y*wb.w + x1.z*wc.w + x1.w*wd.w;
        }
        float4* p0 = (float4*)&xs[(size_t)(a0+rp)*128 + 4*q];
        float4* p1 = (float4*)&xs[(size_t)(a0+rp+8)*128 + 4*q];
        float4 c0 = *p0, c1 = *p1;
        c0.x += ox0*INV_SQRT_F; c0.y += oy0*INV_SQRT_F; c0.z += oz0*INV_SQRT_F; c0.w += ow0*INV_SQRT_F;
        c1.x += ox1*INV_SQRT_F; c1.y += oy1*INV_SQRT_F; c1.z += oz1*INV_SQRT_F; c1.w += ow1*INV_SQRT_F;
        *p0 = c0; *p1 = c1;
    }
}

// ----------------------------------------------------------------
extern "C" void kernel_launch(void* const* d_in, const int* in_sizes, int n_in,
                              void* d_out, int out_size, void* d_ws, size_t ws_size,
                              hipStream_t stream) {
    (void)in_sizes; (void)n_in; (void)out_size; (void)ws_size;
    const int*   Z     = (const int*)  d_in[0];
    const float* r_ij  = (const float*)d_in[1];
    const int*   idx_i = (const int*)  d_in[2];
    const int*   idx_j = (const int*)  d_in[3];
    const float* emb   = (const float*)d_in[4];
    const float* Wpe   = (const float*)d_in[5];
    const float* W0s   = (const float*)d_in[6];
    const float* W0v   = (const float*)d_in[7];
    const float* Wf1   = (const float*)d_in[8];
    const float* bf1   = (const float*)d_in[9];
    const float* Wf2   = (const float*)d_in[10];
    const float* bf2   = (const float*)d_in[11];
    const float* As    = (const float*)d_in[12];
    const float* Av    = (const float*)d_in[13];
    const float* Bs    = (const float*)d_in[14];
    const float* Bv    = (const float*)d_in[15];

    float* xs = (float*)d_out;
    float* ws = (float*)d_ws;
    h2*    fijH = (h2*)ws;                       // NE*10 h2
    float* yvrT = ws + (size_t)NE*10;            // NE*4
    float* xv   = yvrT + (size_t)NE*4;           // NA*384
    _Float16* hsv = (_Float16*)(xv + (size_t)NA*F*3);  // NA*128 f16
    float* aggG = xv + (size_t)NA*F*3 + (size_t)NA*64; // NA*256
    float* AvBv = aggG + (size_t)NA*256;         // 3*64*128
    h2*    Wf2H = (h2*)(AvBv + (size_t)3*64*128);  // 3*128*16 h2
    h2*    Wf1H = Wf2H + (size_t)3*128*16;         // 3*320 h2

    geom_kernel<<<(NE+255)/256, 256, 0, stream>>>(r_ij, fijH, yvrT);
    preph_kernel<<<24, 256, 0, stream>>>(Wf2, Wf1, Wf2H, Wf1H);
    prep2_kernel<<<(3*64*128+255)/256, 256, 0, stream>>>(Av, Bv, AvBv);
    embed_kernel<<<NA/32, 256, 0, stream>>>(Z, emb, Wpe, W0s, xs, hsv);
    hipMemsetAsync(aggG, 0, (size_t)NA*256*sizeof(float), stream);

    for (int l = 0; l < 3; l++) {
        if (l > 0)
            h_kernel<<<NA/16, 256, 0, stream>>>(xs, xv,
                W0s + (size_t)l*F*NF, W0v + (size_t)l*F*NF, hsv);

        if (l < 2)
            agg_kernel<true><<<NE/256, 256, 0, stream>>>(idx_i, idx_j, fijH, yvrT, hsv,
                Wf1H + (size_t)l*320, bf1 + (size_t)l*NF,
                Wf2H + (size_t)l*128*16, bf2 + (size_t)l*6*NF, aggG);
        else
            agg_kernel<false><<<NE/256, 256, 0, stream>>>(idx_i, idx_j, fijH, yvrT, hsv,
                Wf1H + (size_t)l*320, bf1 + (size_t)l*NF,
                Wf2H + (size_t)l*128*16, bf2 + (size_t)l*6*NF, aggG);

        if (l == 0)
            mlp_kernel<true, true, true><<<NA/16, 256, 0, stream>>>(aggG,
                As + (size_t)l*2*NF*F, Bs + (size_t)l*F*F, AvBv + (size_t)l*64*128,
                xs, xv, aggG);
        else if (l == 1)
            mlp_kernel<true, false, true><<<NA/16, 256, 0, stream>>>(aggG,
                As + (size_t)l*2*NF*F, Bs + (size_t)l*F*F, AvBv + (size_t)l*64*128,
                xs, xv, aggG);
        else
            mlp_kernel<false, false, false><<<NA/16, 256, 0, stream>>>(aggG,
                As + (size_t)l*2*NF*F, Bs + (size_t)l*F*F, AvBv + (size_t)l*64*128,
                xs, xv, aggG);
    }
}

// Round 21
// 356.927 us; speedup vs baseline: 1.0477x; 1.0477x over previous
//
#include <hip/hip_runtime.h>
#include <math.h>

constexpr int NA   = 16000;
constexpr int NE   = 256000;
constexpr int F    = 128;
constexpr int NF   = 32;
constexpr int NRBF = 20;
constexpr float CUTOFF       = 5.0f;
constexpr float INV_SQRT_F   = 0.0883883476483184f;  // 1/sqrt(128)
constexpr float INV_SQRT_2NF = 0.125f;               // 1/sqrt(64)
constexpr float INV_SQ3      = 0.5773502691896258f;
constexpr float SQ3          = 1.7320508075688772f;
constexpr float LOG2_        = 0.6931471805599453f;
constexpr float PI_          = 3.14159265358979323f;

typedef _Float16 h2 __attribute__((ext_vector_type(2)));

__device__ __forceinline__ float ssp(float x) {
    return fmaxf(x, 0.0f) + __logf(1.0f + __expf(-fabsf(x))) - LOG2_;
}
__device__ __forceinline__ float fdot2(h2 a, h2 b, float c) {
#if __has_builtin(__builtin_amdgcn_fdot2)
    return __builtin_amdgcn_fdot2(a, b, c, false);
#else
    return c + (float)a[0]*(float)b[0] + (float)a[1]*(float)b[1];
#endif
}

// ---------------------------------------------------------------- K0: per-edge geometry (transposed outputs)
__global__ void geom_kernel(const float* __restrict__ r_ij,
                            float* __restrict__ fijT,
                            float* __restrict__ yvrT) {
    int e = blockIdx.x * blockDim.x + threadIdx.x;
    if (e >= NE) return;
    float x = r_ij[3*e+0], y = r_ij[3*e+1], z = r_ij[3*e+2];
    float d = sqrtf(x*x + y*y + z*z);
    const float delta = CUTOFF / (NRBF - 1);
    const float coeff = -0.5f / (delta * delta);
    #pragma unroll
    for (int k = 0; k < NRBF; k++) {
        float t = d - delta * (float)k;
        fijT[(size_t)k*NE + e] = __expf(coeff * t * t);
    }
    float rc = 0.5f * (__cosf(PI_ * d / CUTOFF) + 1.0f);
    rc = (d < CUTOFF) ? rc : 0.0f;
    float inv = SQ3 / fmaxf(d, 1e-9f);
    yvrT[0*(size_t)NE + e] = x * inv;
    yvrT[1*(size_t)NE + e] = y * inv;
    yvrT[2*(size_t)NE + e] = z * inv;
    yvrT[3*(size_t)NE + e] = rc;
}

// ---------------------------------------------------------------- preph: f16 filter weights
__global__ void preph_kernel(const float* __restrict__ Wf2, const float* __restrict__ Wf1,
                             h2* __restrict__ Wf2H, h2* __restrict__ Wf1H) {
    int u = blockIdx.x * 256 + threadIdx.x;
    if (u < 3*128*16) {
        int l = u / (128*16), rem = u % (128*16), c = rem >> 4, k2 = rem & 15;
        const float* W = Wf2 + (size_t)l*NF*192;
        Wf2H[u] = h2{(_Float16)W[(2*k2)*192 + c], (_Float16)W[(2*k2+1)*192 + c]};
    }
    if (u < 3*320) {
        int l = u / 320, rem = u % 320, k2 = rem >> 5, g = rem & 31;
        const float* W = Wf1 + (size_t)l*NRBF*NF;
        Wf1H[u] = h2{(_Float16)W[(2*k2)*32 + g], (_Float16)W[(2*k2+1)*32 + g]};
    }
}

// ---------------------------------------------------------------- prep2: AvBv[l][f][c] = (Av[l]@Bv[l]) * scale
__global__ void prep2_kernel(const float* __restrict__ Av, const float* __restrict__ Bv,
                             float* __restrict__ AvBv) {
    int u = blockIdx.x * 256 + threadIdx.x;
    if (u >= 3*64*128) return;
    int l = u >> 13, rem = u & 8191, f = rem >> 7, c = rem & 127;
    const float* av = Av + (size_t)l*64*128 + f*128;
    const float* bv = Bv + (size_t)l*128*128 + c;
    float acc = 0.f;
    #pragma unroll 8
    for (int g = 0; g < 128; g++) acc += av[g] * bv[(size_t)g*128];
    AvBv[u] = acc * (INV_SQRT_2NF * INV_SQRT_F);
}

// ---------------------------------------------------------------- K2: xs = emb[Z] @ W_pe (32 atoms/block) + fused hsv(l=0)
__global__ __launch_bounds__(256, 4)
void embed_kernel(const int* __restrict__ Z,
                  const float* __restrict__ emb,
                  const float* __restrict__ Wpe,
                  const float* __restrict__ W0s,
                  float* __restrict__ xs,
                  float* __restrict__ hsv) {
    __shared__ float ER[32][128];
    __shared__ int   Zs[32];
    int t = threadIdx.x;
    int a0 = blockIdx.x * 32;
    if (t < 32) Zs[t] = Z[a0 + t];
    __syncthreads();
    {
        const float4* emb4 = (const float4*)emb;
        float4* ER4 = (float4*)&ER[0][0];
        #pragma unroll
        for (int it = 0; it < 4; it++) {
            int u4 = it*256 + t;
            int a = u4 >> 5, k4 = u4 & 31;
            ER4[u4] = emb4[(size_t)Zs[a]*32 + k4];
        }
    }
    __syncthreads();
    int c = t & 127, half = t >> 7;
    float acc[16];
    #pragma unroll
    for (int a = 0; a < 16; a++) acc[a] = 0.f;
    for (int k = 0; k < 128; k++) {
        float w = Wpe[k*128 + c];
        #pragma unroll
        for (int a = 0; a < 16; a++) acc[a] += ER[half*16 + a][k] * w;
    }
    __syncthreads();   // all ER reads done before overwrite
    #pragma unroll
    for (int a = 0; a < 16; a++) {
        float v = acc[a] * INV_SQRT_F;
        xs[(size_t)(a0 + half*16 + a)*128 + c] = v;
        ER[half*16 + a][c] = v;                 // ER now holds xs (scaled)
    }
    __syncthreads();
    // ---- fused h for layer 0: hs = xs @ W0s * inv ; hv = 0 ----
    {
        int g = t & 31, rr = t >> 5;            // atoms rr*4..rr*4+3
        float a2[4] = {0.f, 0.f, 0.f, 0.f};
        for (int k = 0; k < 128; k++) {
            float w = W0s[k*32 + g];
            #pragma unroll
            for (int a = 0; a < 4; a++) a2[a] += ER[rr*4 + a][k] * w;
        }
        #pragma unroll
        for (int a = 0; a < 4; a++)
            hsv[(size_t)(a0 + rr*4 + a)*128 + g] = a2[a] * INV_SQRT_F;
        for (int u = t; u < 32*96; u += 256) {
            int a = u / 96, rem = u - a*96;
            hsv[(size_t)(a0 + a)*128 + 32 + rem] = 0.f;
        }
    }
}

// ---------------------------------------------------------------- K3: hsv projection (16 atoms/block), l=1,2
__global__ __launch_bounds__(256, 4)
void h_kernel(const float* __restrict__ xs,
              const float* __restrict__ xv,
              const float* __restrict__ W0s,
              const float* __restrict__ W0v,
              float* __restrict__ hsv) {
    __shared__ float X[16][512];
    int t = threadIdx.x;
    int a0 = blockIdx.x * 16;
    {
        float* Xf = &X[0][0];
        const float4* xs4 = (const float4*)xs;
        const float4* xv4 = (const float4*)xv;
        #pragma unroll
        for (int it = 0; it < 2; it++) {
            int u4 = it*256 + t;
            int a = u4 >> 5, k4 = u4 & 31;
            *(float4*)&Xf[a*512 + k4*4] = xs4[(size_t)a0*32 + u4];
        }
        #pragma unroll
        for (int it = 0; it < 6; it++) {
            int u4 = it*256 + t;
            int a = u4 / 96, rem = u4 - a*96;
            *(float4*)&Xf[a*512 + 128 + rem*4] = xv4[(size_t)a0*96 + u4];
        }
    }
    __syncthreads();
    int g = t & 31, r = t >> 5;
    int sel = r & 3, half = r >> 2;
    const float* W = (sel == 0) ? W0s : W0v;
    int xoff = (sel == 0) ? 0 : (128 + (sel-1)*128);
    float acc[8];
    #pragma unroll
    for (int a = 0; a < 8; a++) acc[a] = 0.f;
    for (int k = 0; k < 128; k++) {
        float w = W[k*32 + g];
        #pragma unroll
        for (int a = 0; a < 8; a++) acc[a] += X[half*8 + a][xoff + k] * w;
    }
    #pragma unroll
    for (int a = 0; a < 8; a++) {
        int n = a0 + half*8 + a;
        if (sel == 0) hsv[(size_t)n*128 + g] = acc[a] * INV_SQRT_F;
        else          hsv[(size_t)n*128 + 32 + g*3 + (sel-1)] = acc[a] * INV_SQRT_F;
    }
}

// ---------------------------------------------------------------- K4: edge aggregation, 64 edges/wave, fdot2, pipelined
// aggG row (256): [0..63] s-cols; [64 + c*64 + f] = v_in[f][c].
struct alignas(16) HRow { h2 v[20]; };      // padded to 80B rows

template <bool DO_V>
__global__ __launch_bounds__(256, 4)
void agg_kernel(const int* __restrict__ idx_i,
                const int* __restrict__ idx_j,
                const float* __restrict__ fijT,
                const float* __restrict__ yvrT,
                const float* __restrict__ hsv,
                const h2* __restrict__ Wf1H,
                const float* __restrict__ bf1,
                const h2* __restrict__ Wf2H,
                const float* __restrict__ bf2,
                float* __restrict__ aggG) {
    __shared__ h2 LW1[320];          // 1280 B
    __shared__ HRow HB[4][64];       // 20480 B
    int t = threadIdx.x;
    for (int u = t; u < 320; u += 256) LW1[u] = Wf1H[u];
    __syncthreads();

    int wid = t >> 6, lane = t & 63;
    int base = (blockIdx.x*4 + wid) * 64;

    int   il = idx_i[base + lane];
    int   jl = idx_j[base + lane];
    float y0l = yvrT[0*(size_t)NE + base + lane];
    float y1l = yvrT[1*(size_t)NE + base + lane];
    float y2l = yvrT[2*(size_t)NE + base + lane];
    float y3l = yvrT[3*(size_t)NE + base + lane];

    int ilp = __shfl_up(il, 1);
    unsigned long long bmask = __ballot(lane > 0 && il != ilp);

    // ---- MLP1, lane-per-edge, fdot2 ----
    h2 fp[10];
    #pragma unroll
    for (int k2 = 0; k2 < 10; k2++) {
        float fa = fijT[(size_t)(2*k2)*NE + base + lane];
        float fb = fijT[(size_t)(2*k2+1)*NE + base + lane];
        fp[k2] = h2{(_Float16)fa, (_Float16)fb};
    }
    float h[32];
    #pragma unroll
    for (int g = 0; g < 32; g++) h[g] = bf1[g];
    #pragma unroll
    for (int k2 = 0; k2 < 10; k2++) {
        #pragma unroll
        for (int g = 0; g < 32; g++)
            h[g] = fdot2(fp[k2], LW1[k2*32 + g], h[g]);
    }
    #pragma unroll
    for (int g = 0; g < 32; g++) h[g] = ssp(h[g]);
    {
        h2 hp[16];
        #pragma unroll
        for (int i = 0; i < 16; i++) hp[i] = h2{(_Float16)h[2*i], (_Float16)h[2*i+1]};
        float4* dst = (float4*)HB[wid][lane].v;
        const float4* srcp = (const float4*)hp;
        #pragma unroll
        for (int w = 0; w < 4; w++) dst[w] = srcp[w];
    }

    // ---- per-lane f16 weight columns; asm barrier blocks rematerialization ----
    h2 w2a[16], w2b[16];
    #pragma unroll
    for (int k2 = 0; k2 < 16; k2++) {
        w2a[k2] = Wf2H[lane*16 + k2];
        asm volatile("" : "+v"(w2a[k2]));
    }
    if (DO_V) {
        #pragma unroll
        for (int k2 = 0; k2 < 16; k2++) {
            w2b[k2] = Wf2H[(64+lane)*16 + k2];
            asm volatile("" : "+v"(w2b[k2]));
        }
    }
    float bf2a = bf2[lane];
    float bf2b = DO_V ? bf2[64 + lane] : 0.f;

    int idxQ = 32 + 3*(lane - 32);
    int off0 = (lane < 32) ? lane : idxQ;
    int off1 = (lane < 32) ? lane : (idxQ + 1);
    int off2 = (lane < 32) ? lane : (idxQ + 2);

    float a0 = 0.f, a1 = 0.f, a2 = 0.f, a3 = 0.f;
    int prev = __builtin_amdgcn_readlane(il, 0);

    // ---- software-pipelined edge loop: prefetch ii+1 while computing ii ----
    float qn0, qn1, qn2;
    float4 hbn[4];
    {
        int j = __builtin_amdgcn_readlane(jl, 0);
        const float* row = hsv + (size_t)j*128;
        qn0 = row[off0]; qn1 = row[off1]; qn2 = row[off2];
        const float4* hq4 = (const float4*)HB[wid][0].v;
        hbn[0] = hq4[0]; hbn[1] = hq4[1]; hbn[2] = hq4[2]; hbn[3] = hq4[3];
    }
    for (int ii = 0; ii < 64; ++ii) {
        float q0 = qn0, q1 = qn1, q2 = qn2;
        float4 hbc[4] = { hbn[0], hbn[1], hbn[2], hbn[3] };
        if (ii < 63) {
            int j = __builtin_amdgcn_readlane(jl, ii + 1);
            const float* row = hsv + (size_t)j*128;
            qn0 = row[off0]; qn1 = row[off1]; qn2 = row[off2];
            const float4* hq4 = (const float4*)HB[wid][ii + 1].v;
            hbn[0] = hq4[0]; hbn[1] = hq4[1]; hbn[2] = hq4[2]; hbn[3] = hq4[3];
        }
        if ((bmask >> ii) & 1ull) {
            unsafeAtomicAdd(&aggG[(size_t)prev*256 + lane], a0);
            a0 = 0.f;
            if (DO_V) {
                unsafeAtomicAdd(&aggG[(size_t)prev*256 + 64 + lane],  a1);
                unsafeAtomicAdd(&aggG[(size_t)prev*256 + 128 + lane], a2);
                unsafeAtomicAdd(&aggG[(size_t)prev*256 + 192 + lane], a3);
                a1 = a2 = a3 = 0.f;
            }
            prev = __builtin_amdgcn_readlane(il, ii);
        }
        // MLP2 with prefetched h1 row, reg weights
        float s0 = bf2a, s1 = bf2b;
        {
            const h2* hh = (const h2*)hbc;
            #pragma unroll
            for (int k2 = 0; k2 < 16; k2++) {
                s0 = fdot2(hh[k2], w2a[k2], s0);
                if (DO_V) s1 = fdot2(hh[k2], w2b[k2], s1);
            }
        }
        float y3s = __int_as_float(__builtin_amdgcn_readlane(__float_as_int(y3l), ii));
        float y0s = __int_as_float(__builtin_amdgcn_readlane(__float_as_int(y0l), ii));
        float y1s = __int_as_float(__builtin_amdgcn_readlane(__float_as_int(y1l), ii));
        float y2s = __int_as_float(__builtin_amdgcn_readlane(__float_as_int(y2l), ii));
        float w0 = s0 * y3s;
        float dot = (q0*y0s + q1*y1s + q2*y2s) * INV_SQ3;
        float v0 = (lane < 32) ? q0 : dot;
        a0 += v0 * w0;
        if (DO_V) {
            float w1 = s1 * y3s;
            float m1 = (lane < 32) ? y0s : 1.0f;
            float m2 = (lane < 32) ? y1s : 1.0f;
            float m3 = (lane < 32) ? y2s : 1.0f;
            a1 += q0 * m1 * w1;
            a2 += q1 * m2 * w1;
            a3 += q2 * m3 * w1;
        }
    }
    unsafeAtomicAdd(&aggG[(size_t)prev*256 + lane], a0);
    if (DO_V) {
        unsafeAtomicAdd(&aggG[(size_t)prev*256 + 64 + lane],  a1);
        unsafeAtomicAdd(&aggG[(size_t)prev*256 + 128 + lane], a2);
        unsafeAtomicAdd(&aggG[(size_t)prev*256 + 192 + lane], a3);
    }
}

// ---------------------------------------------------------------- K5: batched atom-side MLP (re-zeros aggG for next layer)
template <bool DO_V, bool XV_WRITE, bool ZERO_AGG>
__global__ __launch_bounds__(256, 4)
void mlp_kernel(const float* __restrict__ aggG,
                const float* __restrict__ As,
                const float* __restrict__ Bs,
                const float* __restrict__ AvBv,
                float* __restrict__ xs,
                float* __restrict__ xv,
                float* __restrict__ aggW) {
    constexpr int AC = DO_V ? 256 : 64;
    __shared__ float aggL[16][AC];
    __shared__ float outL[16][128];
    int t = threadIdx.x;
    int a0 = blockIdx.x * 16;
    {
        const float4* g4 = (const float4*)(aggG + (size_t)a0*256);
        if (DO_V) {
            float4* l4 = (float4*)&aggL[0][0];
            #pragma unroll
            for (int it = 0; it < 4; it++) l4[it*256 + t] = g4[it*256 + t];
        } else {
            int row = t >> 4, c4 = t & 15;
            *(float4*)&aggL[row][c4*4] = g4[row*64 + c4];
        }
    }
    __syncthreads();
    if (ZERO_AGG) {    // after barrier: loads complete; re-zero for next layer
        float4 z = make_float4(0.f, 0.f, 0.f, 0.f);
        float4* g4w = (float4*)(aggW + (size_t)a0*256);
        #pragma unroll
        for (int it = 0; it < 4; it++) g4w[it*256 + t] = z;
    }

    int q  = t & 31;
    int rp = t >> 5;
    const float4* As4 = (const float4*)As;
    const float4* Bs4 = (const float4*)Bs;

    // ---- stage 1 s ----
    {
        float ox0=0,oy0=0,oz0=0,ow0=0, ox1=0,oy1=0,oz1=0,ow1=0;
        const float4* x0p = (const float4*)&aggL[rp][0];
        const float4* x1p = (const float4*)&aggL[rp+8][0];
        #pragma unroll 4
        for (int kq = 0; kq < 16; kq++) {
            float4 x0 = x0p[kq], x1 = x1p[kq];
            float4 wa = As4[(4*kq+0)*32 + q];
            float4 wb = As4[(4*kq+1)*32 + q];
            float4 wc = As4[(4*kq+2)*32 + q];
            float4 wd = As4[(4*kq+3)*32 + q];
            ox0 += x0.x*wa.x + x0.y*wb.x + x0.z*wc.x + x0.w*wd.x;
            oy0 += x0.x*wa.y + x0.y*wb.y + x0.z*wc.y + x0.w*wd.y;
            oz0 += x0.x*wa.z + x0.y*wb.z + x0.z*wc.z + x0.w*wd.z;
            ow0 += x0.x*wa.w + x0.y*wb.w + x0.z*wc.w + x0.w*wd.w;
            ox1 += x1.x*wa.x + x1.y*wb.x + x1.z*wc.x + x1.w*wd.x;
            oy1 += x1.x*wa.y + x1.y*wb.y + x1.z*wc.y + x1.w*wd.y;
            oz1 += x1.x*wa.z + x1.y*wb.z + x1.z*wc.z + x1.w*wd.z;
            ow1 += x1.x*wa.w + x1.y*wb.w + x1.z*wc.w + x1.w*wd.w;
        }
        float4 r0 = { ssp(ox0*INV_SQRT_2NF), ssp(oy0*INV_SQRT_2NF), ssp(oz0*INV_SQRT_2NF), ssp(ow0*INV_SQRT_2NF) };
        float4 r1 = { ssp(ox1*INV_SQRT_2NF), ssp(oy1*INV_SQRT_2NF), ssp(oz1*INV_SQRT_2NF), ssp(ow1*INV_SQRT_2NF) };
        *(float4*)&outL[rp][4*q]   = r0;
        *(float4*)&outL[rp+8][4*q] = r1;
    }
    // ---- v path: xv (+)= v_in @ AvBv ----
    if (DO_V) {
        const float4* AB4 = (const float4*)AvBv;
        int ra[6], rc[6];
        #pragma unroll
        for (int i = 0; i < 6; i++) {
            int rv = rp + 8*i;
            ra[i] = rv/3; rc[i] = rv - 3*(rv/3);
        }
        float o[6][4];
        #pragma unroll
        for (int i = 0; i < 6; i++) { o[i][0]=0; o[i][1]=0; o[i][2]=0; o[i][3]=0; }
        const float4* vp[6];
        #pragma unroll
        for (int i = 0; i < 6; i++)
            vp[i] = (const float4*)&aggL[ra[i]][64 + rc[i]*64];
        #pragma unroll 2
        for (int kq = 0; kq < 16; kq++) {
            float4 wa = AB4[(4*kq+0)*32 + q];
            float4 wb = AB4[(4*kq+1)*32 + q];
            float4 wc = AB4[(4*kq+2)*32 + q];
            float4 wd = AB4[(4*kq+3)*32 + q];
            #pragma unroll
            for (int i = 0; i < 6; i++) {
                float4 x = vp[i][kq];
                o[i][0] += x.x*wa.x + x.y*wb.x + x.z*wc.x + x.w*wd.x;
                o[i][1] += x.x*wa.y + x.y*wb.y + x.z*wc.y + x.w*wd.y;
                o[i][2] += x.x*wa.z + x.y*wb.z + x.z*wc.z + x.w*wd.z;
                o[i][3] += x.x*wa.w + x.y*wb.w + x.z*wc.w + x.w*wd.w;
            }
        }
        #pragma unroll
        for (int i = 0; i < 6; i++) {
            float4* p = (float4*)&xv[(size_t)(a0+ra[i])*384 + rc[i]*128 + 4*q];
            if (XV_WRITE) {
                float4 c = make_float4(o[i][0], o[i][1], o[i][2], o[i][3]);
                *p = c;
            } else {
                float4 c = *p;
                c.x += o[i][0]; c.y += o[i][1]; c.z += o[i][2]; c.w += o[i][3];
                *p = c;
            }
        }
    }
    __syncthreads();
    // ---- stage 2 s: xs += os1 @ Bs ----
    {
        float ox0=0,oy0=0,oz0=0,ow0=0, ox1=0,oy1=0,oz1=0,ow1=0;
        const float4* x0p = (const float4*)&outL[rp][0];
        const float4* x1p = (const float4*)&outL[rp+8][0];
        #pragma unroll 4
        for (int kq = 0; kq < 32; kq++) {
            float4 x0 = x0p[kq], x1 = x1p[kq];
            float4 wa = Bs4[(4*kq+0)*32 + q];
            float4 wb = Bs4[(4*kq+1)*32 + q];
            float4 wc = Bs4[(4*kq+2)*32 + q];
            float4 wd = Bs4[(4*kq+3)*32 + q];
            ox0 += x0.x*wa.x + x0.y*wb.x + x0.z*wc.x + x0.w*wd.x;
            oy0 += x0.x*wa.y + x0.y*wb.y + x0.z*wc.y + x0.w*wd.y;
            oz0 += x0.x*wa.z + x0.y*wb.z + x0.z*wc.z + x0.w*wd.z;
            ow0 += x0.x*wa.w + x0.y*wb.w + x0.z*wc.w + x0.w*wd.w;
            ox1 += x1.x*wa.x + x1.y*wb.x + x1.z*wc.x + x1.w*wd.x;
            oy1 += x1.x*wa.y + x1.y*wb.y + x1.z*wc.y + x1.w*wd.y;
            oz1 += x1.x*wa.z + x1.y*wb.z + x1.z*wc.z + x1.w*wd.z;
            ow1 += x1.x*wa.w + x1.y*wb.w + x1.z*wc.w + x1.w*wd.w;
        }
        float4* p0 = (float4*)&xs[(size_t)(a0+rp)*128 + 4*q];
        float4* p1 = (float4*)&xs[(size_t)(a0+rp+8)*128 + 4*q];
        float4 c0 = *p0, c1 = *p1;
        c0.x += ox0*INV_SQRT_F; c0.y += oy0*INV_SQRT_F; c0.z += oz0*INV_SQRT_F; c0.w += ow0*INV_SQRT_F;
        c1.x += ox1*INV_SQRT_F; c1.y += oy1*INV_SQRT_F; c1.z += oz1*INV_SQRT_F; c1.w += ow1*INV_SQRT_F;
        *p0 = c0; *p1 = c1;
    }
}

// ----------------------------------------------------------------
extern "C" void kernel_launch(void* const* d_in, const int* in_sizes, int n_in,
                              void* d_out, int out_size, void* d_ws, size_t ws_size,
                              hipStream_t stream) {
    (void)in_sizes; (void)n_in; (void)out_size; (void)ws_size;
    const int*   Z     = (const int*)  d_in[0];
    const float* r_ij  = (const float*)d_in[1];
    const int*   idx_i = (const int*)  d_in[2];
    const int*   idx_j = (const int*)  d_in[3];
    const float* emb   = (const float*)d_in[4];
    const float* Wpe   = (const float*)d_in[5];
    const float* W0s   = (const float*)d_in[6];
    const float* W0v   = (const float*)d_in[7];
    const float* Wf1   = (const float*)d_in[8];
    const float* bf1   = (const float*)d_in[9];
    const float* Wf2   = (const float*)d_in[10];
    const float* bf2   = (const float*)d_in[11];
    const float* As    = (const float*)d_in[12];
    const float* Av    = (const float*)d_in[13];
    const float* Bs    = (const float*)d_in[14];
    const float* Bv    = (const float*)d_in[15];

    float* xs = (float*)d_out;
    float* ws = (float*)d_ws;
    float* fijT = ws;                      // NE*20
    float* yvrT = fijT + (size_t)NE*NRBF;  // NE*4
    float* xv   = yvrT + (size_t)NE*4;     // NA*384  ([n][3][128])
    float* hsv  = xv   + (size_t)NA*F*3;   // NA*128
    float* aggG = hsv  + (size_t)NA*F;     // NA*256
    float* AvBv = aggG + (size_t)NA*256;   // 3*64*128
    h2*    Wf2H = (h2*)(AvBv + (size_t)3*64*128);  // 3*128*16 h2
    h2*    Wf1H = Wf2H + (size_t)3*128*16;         // 3*320 h2

    geom_kernel<<<(NE+255)/256, 256, 0, stream>>>(r_ij, fijT, yvrT);
    preph_kernel<<<24, 256, 0, stream>>>(Wf2, Wf1, Wf2H, Wf1H);
    prep2_kernel<<<(3*64*128+255)/256, 256, 0, stream>>>(Av, Bv, AvBv);
    embed_kernel<<<NA/32, 256, 0, stream>>>(Z, emb, Wpe, W0s, xs, hsv);
    hipMemsetAsync(aggG, 0, (size_t)NA*256*sizeof(float), stream);

    for (int l = 0; l < 3; l++) {
        if (l > 0)
            h_kernel<<<NA/16, 256, 0, stream>>>(xs, xv,
                W0s + (size_t)l*F*NF, W0v + (size_t)l*F*NF, hsv);

        if (l < 2)
            agg_kernel<true><<<NE/256, 256, 0, stream>>>(idx_i, idx_j, fijT, yvrT, hsv,
                Wf1H + (size_t)l*320, bf1 + (size_t)l*NF,
                Wf2H + (size_t)l*128*16, bf2 + (size_t)l*6*NF, aggG);
        else
            agg_kernel<false><<<NE/256, 256, 0, stream>>>(idx_i, idx_j, fijT, yvrT, hsv,
                Wf1H + (size_t)l*320, bf1 + (size_t)l*NF,
                Wf2H + (size_t)l*128*16, bf2 + (size_t)l*6*NF, aggG);

        if (l == 0)
            mlp_kernel<true, true, true><<<NA/16, 256, 0, stream>>>(aggG,
                As + (size_t)l*2*NF*F, Bs + (size_t)l*F*F, AvBv + (size_t)l*64*128,
                xs, xv, aggG);
        else if (l == 1)
            mlp_kernel<true, false, true><<<NA/16, 256, 0, stream>>>(aggG,
                As + (size_t)l*2*NF*F, Bs + (size_t)l*F*F, AvBv + (size_t)l*64*128,
                xs, xv, aggG);
        else
            mlp_kernel<false, false, false><<<NA/16, 256, 0, stream>>>(aggG,
                As + (size_t)l*2*NF*F, Bs + (size_t)l*F*F, AvBv + (size_t)l*64*128,
                xs, xv, aggG);
    }
}